// Round 5
// baseline (8605.426 us; speedup 1.0000x reference)
//
#include <hip/hip_runtime.h>

// Seq2Seq round 5: persistent encoder/decoder kernels with device-scope
// barriers; 11 launches total (was ~290). f32 inputs, bf16 MFMA pipeline.

typedef unsigned short u16;
typedef __attribute__((ext_vector_type(8))) short bf16x8;
typedef __attribute__((ext_vector_type(4))) float f32x4;

#define DEVFN static __device__ __forceinline__
#define HBUF ((size_t)4 * 128 * 256)

DEVFN float bf2f(u16 u) {
  unsigned int x = ((unsigned int)u) << 16;
  float f; __builtin_memcpy(&f, &x, 4); return f;
}
DEVFN u16 f2bf(float f) {
  unsigned int x; __builtin_memcpy(&x, &f, 4);
  x = (x + 0x7fffu + ((x >> 16) & 1u)) >> 16;
  return (u16)x;
}
DEVFN float sigf(float x) { return 1.f / (1.f + __expf(-x)); }
DEVFN bf16x8 load8(const u16* p) { return *(const bf16x8*)p; }
DEVFN int clampi(int v, int lo, int hi) { return v < lo ? lo : (v > hi ? hi : v); }

// Device-scope barrier: bar[0]=counter, bar[1]=generation.
DEVFN void gbar(int* bar, int nblk) {
  __syncthreads();  // drains vmcnt before s_barrier -> stores are in L2
  if (threadIdx.x == 0) {
    __threadfence();  // L2 writeback (device visibility)
    int g = __hip_atomic_load(bar + 1, __ATOMIC_RELAXED, __HIP_MEMORY_SCOPE_AGENT);
    int prev = __hip_atomic_fetch_add(bar, 1, __ATOMIC_ACQ_REL, __HIP_MEMORY_SCOPE_AGENT);
    if (prev == nblk - 1) {
      __hip_atomic_store(bar, 0, __ATOMIC_RELAXED, __HIP_MEMORY_SCOPE_AGENT);
      __hip_atomic_fetch_add(bar + 1, 1, __ATOMIC_ACQ_REL, __HIP_MEMORY_SCOPE_AGENT);
    } else {
      while (__hip_atomic_load(bar + 1, __ATOMIC_ACQUIRE, __HIP_MEMORY_SCOPE_AGENT) == g)
        __builtin_amdgcn_s_sleep(2);
    }
    __threadfence();  // invalidate caches (acquire)
  }
  __syncthreads();
}

__global__ void bar_init(int* bars) {
  int i = threadIdx.x;
  for (int k = i; k < 1024; k += 256) bars[k] = 0;
}

// ---------------------------------------------------------------------------
// Generic MFMA GEMM (standalone launches): out[m,n] = sum_k A[m,k]*W[n,k]
// EPI 0: f32 out (+bias). EPI 1: bf16 out (+bias).
// ---------------------------------------------------------------------------
struct GemmArgs {
  const u16* A; int lda; int M;
  const u16* W; int ldw; int N; int K;
  void* out; int ldc;
  const float* bias;
};

template <int EPI>
__global__ __launch_bounds__(256) void gemm_k(GemmArgs g) {
  int lane = threadIdx.x & 63, wave = threadIdx.x >> 6;
  int col = lane & 15, q = lane >> 4;
  int m0 = blockIdx.x * 64 + (wave >> 1) * 32;
  int n0 = blockIdx.y * 64 + (wave & 1) * 32;
  f32x4 acc[2][2] = {};
  int rA[2] = { m0 + col, m0 + 16 + col };
  int rB[2] = { n0 + col, n0 + 16 + col };
  bool gA[2] = { rA[0] < g.M, rA[1] < g.M };
  bool gB[2] = { rB[0] < g.N, rB[1] < g.N };
  const u16* pA[2]; const u16* pB[2];
#pragma unroll
  for (int i = 0; i < 2; i++) {
    pA[i] = g.A + (size_t)(gA[i] ? rA[i] : 0) * g.lda + q * 8;
    pB[i] = g.W + (size_t)(gB[i] ? rB[i] : 0) * g.ldw + q * 8;
  }
  bf16x8 zf = {0,0,0,0,0,0,0,0};
  for (int k = 0; k < g.K; k += 32) {
    bf16x8 a0 = gA[0] ? load8(pA[0] + k) : zf;
    bf16x8 a1 = gA[1] ? load8(pA[1] + k) : zf;
    bf16x8 b0 = gB[0] ? load8(pB[0] + k) : zf;
    bf16x8 b1 = gB[1] ? load8(pB[1] + k) : zf;
    acc[0][0] = __builtin_amdgcn_mfma_f32_16x16x32_bf16(a0, b0, acc[0][0], 0, 0, 0);
    acc[0][1] = __builtin_amdgcn_mfma_f32_16x16x32_bf16(a0, b1, acc[0][1], 0, 0, 0);
    acc[1][0] = __builtin_amdgcn_mfma_f32_16x16x32_bf16(a1, b0, acc[1][0], 0, 0, 0);
    acc[1][1] = __builtin_amdgcn_mfma_f32_16x16x32_bf16(a1, b1, acc[1][1], 0, 0, 0);
  }
#pragma unroll
  for (int mi = 0; mi < 2; mi++)
#pragma unroll
    for (int ni = 0; ni < 2; ni++)
#pragma unroll
      for (int r = 0; r < 4; r++) {
        int m = m0 + mi * 16 + q * 4 + r;
        int n = n0 + ni * 16 + col;
        if (m >= g.M || n >= g.N) continue;
        float v = acc[mi][ni][r];
        if (g.bias) v += g.bias[n];
        if constexpr (EPI == 0) ((float*)g.out)[(size_t)m * g.ldc + n] = v;
        else ((u16*)g.out)[(size_t)m * g.ldc + n] = f2bf(v);
      }
}

// ---------------------------------------------------------------------------
// prep kernels
// ---------------------------------------------------------------------------
struct CvtAll {
  const float* src[12]; u16* dst[12];
  int R[12], C[12], ld[12], c0[12], blk0[13];
};
__global__ __launch_bounds__(256) void cvt_all_k(CvtAll a) {
  int blk = blockIdx.x, s = 0;
  while (s < 11 && blk >= a.blk0[s + 1]) s++;
  int idx = (blk - a.blk0[s]) * 256 + threadIdx.x;
  int n = a.R[s] * a.C[s];
  if (idx >= n) return;
  int r = idx / a.C[s], c = idx - r * a.C[s];
  a.dst[s][idx] = f2bf(a.src[s][(size_t)r * a.ld[s] + a.c0[s] + c]);
}

// WcT[n*512+d] = bf16(W_c[d*512+n])
__global__ void cvt_T(const float* in, u16* out) {
  int idx = blockIdx.x * 256 + threadIdx.x;  // 262144
  int n = idx >> 9, d = idx & 511;
  out[idx] = f2bf(in[(size_t)d * 512 + n]);
}

__global__ void smallprep(const float* bihf, const float* bhhf, const float* bihb, const float* bhhb,
                          const float* Wbdb, const float* h2ab, const float* dbih, const float* dbhh,
                          float* bias_f, float* bias_b, float* bwbd, float* bh2a, float* bdecint) {
  int i = blockIdx.x * 256 + threadIdx.x;
  if (i < 1024) bias_f[i] = bihf[i] + bhhf[i];
  else if (i < 2048) { int k = i - 1024; bias_b[k] = bihb[k] + bhhb[k]; }
  else if (i < 2560) { int k = i - 2048; bwbd[k] = Wbdb[k]; }
  else if (i < 2660) { int k = i - 2560; bh2a[k] = h2ab[k]; }
  else if (i < 4708) { int r = i - 2660; int j = r >> 2, gg = r & 3; bdecint[r] = dbih[gg * 512 + j] + dbhh[gg * 512 + j]; }
}

__global__ void wsum_build(const float* Wbd, u16* Wsum) {
  int idx = blockIdx.x * 256 + threadIdx.x;  // 512*896
  int n = idx / 896, j = idx % 896;
  int c1 = (j < 448) ? (1024 + j) : (1920 + (j - 448));
  int c2 = c1 + 448;
  Wsum[idx] = f2bf(Wbd[(size_t)n * 2944 + c1] + Wbd[(size_t)n * 2944 + c2]);
}

// ---------------------------------------------------------------------------
// Env encoder (unchanged): 1792 4-step LSTM chains -> ctx_cat(B,896) bf16
// ---------------------------------------------------------------------------
__global__ __launch_bounds__(256) void env_encode(
    const int* cur_env, const int* ini_env,
    const float* color_emb, const float* pos_emb,
    const float* wih, const float* whh, const float* bih, const float* bhh,
    u16* ctx_cat) {
  __shared__ float s_wih[128 * 33], s_whh[128 * 33], s_b[128], s_col[7 * 32];
  __shared__ float h_lds[8][33];
  int tid = threadIdx.x;
  for (int i = tid; i < 128 * 32; i += 256) {
    int r = i >> 5, k2 = i & 31;
    s_wih[r * 33 + k2] = wih[i];
    s_whh[r * 33 + k2] = whh[i];
  }
  for (int i = tid; i < 128; i += 256) s_b[i] = bih[i] + bhh[i];
  for (int i = tid; i < 224; i += 256) s_col[i] = color_emb[i];
  int sl = tid >> 5, j = tid & 31;
  int gseq = blockIdx.x * 8 + sl;
  int e = gseq / 896, rem = gseq % 896;
  int b = rem / 7, p = rem % 7;
  const int* env = e ? ini_env : cur_env;
  int eoff = e ? 0 : 448;
  h_lds[sl][j] = 0.f;
  __syncthreads();
  float cj = 0.f, hj = 0.f;
  for (int st = 0; st < 4; st++) {
    int tok = clampi(env[b * 35 + p * 5 + 1 + st], 0, 6);
    const float* x = &s_col[tok * 32];
    float pi = s_b[j], pf = s_b[32 + j], pg = s_b[64 + j], po = s_b[96 + j];
    for (int k = 0; k < 32; k++) {
      float xk = x[k], hk = h_lds[sl][k];
      pi += s_wih[j * 33 + k] * xk + s_whh[j * 33 + k] * hk;
      pf += s_wih[(32 + j) * 33 + k] * xk + s_whh[(32 + j) * 33 + k] * hk;
      pg += s_wih[(64 + j) * 33 + k] * xk + s_whh[(64 + j) * 33 + k] * hk;
      po += s_wih[(96 + j) * 33 + k] * xk + s_whh[(96 + j) * 33 + k] * hk;
    }
    cj = sigf(pf) * cj + sigf(pi) * tanhf(pg);
    hj = sigf(po) * tanhf(cj);
    __syncthreads();
    h_lds[sl][j] = hj;
    __syncthreads();
  }
  size_t base = (size_t)b * 896 + eoff + p * 64;
  ctx_cat[base + j] = f2bf(pos_emb[p * 32 + j]);
  ctx_cat[base + 32 + j] = f2bf(hj);
}

// ---------------------------------------------------------------------------
// Persistent encoder: 128 blocks = 4 chains x 8 sgrp x 4 jq; t-loop inside,
// 4-block group barriers (group = chain*8+sgrp shares h). c in registers.
// ---------------------------------------------------------------------------
__global__ __launch_bounds__(256) void enc_persist(
    const int* ins_tok, const int* his_tok,
    const u16* enc_emb, const u16* wih_f, const u16* wih_b,
    const u16* whh_f, const u16* whh_b,
    const float* bias_f, const float* bias_b,
    u16* h_enc, u16* ins_enc, u16* his_enc, int* bars) {
  int blk = blockIdx.x;
  int chain = blk >> 5, sgrp = (blk >> 2) & 7, jq = blk & 3;
  int w = threadIdx.x >> 6, lane = threadIdx.x & 63;
  int col = lane & 15, q = lane >> 4;
  int dir = chain & 1, his = chain >> 1;
  int L = his ? 128 : 64;
  const int* toks = his ? his_tok : ins_tok;
  const u16* wih = dir ? wih_b : wih_f;
  const u16* whh = dir ? whh_b : whh_f;
  const float* bias = dir ? bias_b : bias_f;
  u16* out = his ? his_enc : ins_enc;
  int* bar = bars + (blk >> 2) * 16;
  int jw = jq * 64 + w * 16;
  int j = jw + col;
  float bi = bias[j], bf = bias[256 + j], bg = bias[512 + j], bo = bias[768 + j];
  float creg[4] = {0.f, 0.f, 0.f, 0.f};
  const u16* wrow_x[4]; const u16* wrow_h[4];
#pragma unroll
  for (int G = 0; G < 4; G++) {
    wrow_x[G] = wih + (size_t)(G * 256 + jw + col) * 128 + q * 8;
    wrow_h[G] = whh + (size_t)(G * 256 + jw + col) * 256 + q * 8;
  }
  __shared__ int tok_lds[16];
  for (int t = 0; t < L; t++) {
    int t_x = dir ? (L - 1 - t) : t;
    if (threadIdx.x < 16)
      tok_lds[threadIdx.x] = clampi(toks[(sgrp * 16 + threadIdx.x) * L + t_x], 0, 1999);
    __syncthreads();
    f32x4 acc[4] = {};
    {
      const u16* xrow = enc_emb + (size_t)tok_lds[col] * 128 + q * 8;
      for (int k = 0; k < 128; k += 32) {
        bf16x8 a = load8(xrow + k);
#pragma unroll
        for (int G = 0; G < 4; G++)
          acc[G] = __builtin_amdgcn_mfma_f32_16x16x32_bf16(a, load8(wrow_x[G] + k), acc[G], 0, 0, 0);
      }
    }
    if (t > 0) {
      const u16* hrow = h_enc + ((size_t)((t & 1) ^ 1)) * HBUF + (size_t)chain * 128 * 256
                        + (size_t)(sgrp * 16 + col) * 256 + q * 8;
      for (int k = 0; k < 256; k += 32) {
        bf16x8 a = load8(hrow + k);
#pragma unroll
        for (int G = 0; G < 4; G++)
          acc[G] = __builtin_amdgcn_mfma_f32_16x16x32_bf16(a, load8(wrow_h[G] + k), acc[G], 0, 0, 0);
      }
    }
    u16* h_wr = h_enc + ((size_t)(t & 1)) * HBUF + (size_t)chain * 128 * 256;
#pragma unroll
    for (int r = 0; r < 4; r++) {
      int b = sgrp * 16 + q * 4 + r;
      float pi = acc[0][r] + bi, pf = acc[1][r] + bf;
      float pg = acc[2][r] + bg, po = acc[3][r] + bo;
      float cn = sigf(pf) * creg[r] + sigf(pi) * tanhf(pg);
      creg[r] = cn;
      u16 hb = f2bf(sigf(po) * tanhf(cn));
      h_wr[b * 256 + j] = hb;
      out[((size_t)b * L + t_x) * 512 + dir * 256 + j] = hb;
    }
    gbar(bar, 4);
  }
}

// ---------------------------------------------------------------------------
// Persistent decoder: 128 blocks, 32 steps x 5 phases + logits tail.
// ---------------------------------------------------------------------------
__global__ __launch_bounds__(256) void dec_persist(
    const u16* A_c, const u16* insenc, const u16* hisenc,
    const u16* wp_bf, const u16* wbd01_bf,
    const u16* dwih_bf, const u16* dwhh_bf,
    const float* bdecint, const float* hkbase, const float* projact,
    const int* actions, const float* h0, const float* c0,
    float* u_p, u16* qbuf, u16* qattn, u16* zin, u16* outs,
    const u16* h2a_bf, const float* bh2a, float* logits,
    int* bar) {
  int blk = blockIdx.x, tid = threadIdx.x;
  int lane = tid & 63, wave = tid >> 6, col = lane & 15, q = lane >> 4;
  __shared__ float smem[64 * 68];
  float* h_s = smem;        // 512
  float* red = smem + 512;  // 256
  float* aw  = smem + 768;  // 128
  float* mr  = smem + 896;  // 2
  float creg[4] = {0.f, 0.f, 0.f, 0.f};

  // init: zin parity0 h-half and qbuf h-half from h0
  for (int d = tid; d < 512; d += 256) {
    u16 hv = f2bf(h0[blk * 512 + d]);
    zin[(size_t)blk * 1024 + 512 + d] = hv;
    qbuf[(size_t)blk * 1024 + d] = hv;
  }
  gbar(bar, 128);

  for (int t = 0; t < 32; t++) {
    u16* zin_cur = zin + (size_t)(t & 1) * 128 * 1024;
    u16* zin_nxt = zin + (size_t)((t + 1) & 1) * 128 * 1024;

    // ---- Phase 1: per-sample attn1 via A_c . h ----
    {
      int b = blk;
      for (int d = tid; d < 512; d += 256) h_s[d] = bf2f(qbuf[(size_t)b * 1024 + d]);
      __syncthreads();
      {
        int l = tid >> 2, part = tid & 3;
        const u16* row = A_c + ((size_t)b * 64 + l) * 512 + part * 128;
        float s = 0.f;
        for (int k = 0; k < 128; k += 8) {
          bf16x8 v = load8(row + k);
#pragma unroll
          for (int e = 0; e < 8; e++) s += bf2f((u16)v[e]) * h_s[part * 128 + k + e];
        }
        red[tid] = s;
      }
      __syncthreads();
      if (tid < 64) {
        float sc = red[tid * 4] + red[tid * 4 + 1] + red[tid * 4 + 2] + red[tid * 4 + 3];
        float m = sc;
        for (int off = 32; off > 0; off >>= 1) m = fmaxf(m, __shfl_xor(m, off));
        float e = __expf(sc - m);
        float sm = e;
        for (int off = 32; off > 0; off >>= 1) sm += __shfl_xor(sm, off);
        aw[tid] = e / sm;
      }
      __syncthreads();
      for (int d = tid; d < 512; d += 256) {
        float z = 0.f;
        for (int l = 0; l < 64; l++) z += aw[l] * bf2f(insenc[((size_t)b * 64 + l) * 512 + d]);
        u16 zb = f2bf(z);
        qattn[(size_t)b * 1024 + d] = zb;
        qbuf[(size_t)b * 1024 + 512 + d] = zb;
      }
    }
    gbar(bar, 128);

    // ---- Phase 2: u_p = W_p @ [h|z_c]  (16 blocks) ----
    if (blk < 16) {
      int m0 = (blk & 1) * 64 + (wave >> 1) * 32;
      int n0 = (blk >> 1) * 64 + (wave & 1) * 32;
      f32x4 acc[2][2] = {};
      const u16* pA[2]; const u16* pB[2];
#pragma unroll
      for (int i = 0; i < 2; i++) {
        pA[i] = qbuf + (size_t)(m0 + i * 16 + col) * 1024 + q * 8;
        pB[i] = wp_bf + (size_t)(n0 + i * 16 + col) * 1024 + q * 8;
      }
      for (int k = 0; k < 1024; k += 32) {
        bf16x8 a0 = load8(pA[0] + k), a1 = load8(pA[1] + k);
        bf16x8 b0 = load8(pB[0] + k), b1 = load8(pB[1] + k);
        acc[0][0] = __builtin_amdgcn_mfma_f32_16x16x32_bf16(a0, b0, acc[0][0], 0, 0, 0);
        acc[0][1] = __builtin_amdgcn_mfma_f32_16x16x32_bf16(a0, b1, acc[0][1], 0, 0, 0);
        acc[1][0] = __builtin_amdgcn_mfma_f32_16x16x32_bf16(a1, b0, acc[1][0], 0, 0, 0);
        acc[1][1] = __builtin_amdgcn_mfma_f32_16x16x32_bf16(a1, b1, acc[1][1], 0, 0, 0);
      }
#pragma unroll
      for (int mi = 0; mi < 2; mi++)
#pragma unroll
        for (int ni = 0; ni < 2; ni++)
#pragma unroll
          for (int r = 0; r < 4; r++)
            u_p[(size_t)(m0 + mi * 16 + q * 4 + r) * 512 + (n0 + ni * 16 + col)] = acc[mi][ni][r];
    }
    gbar(bar, 128);

    // ---- Phase 3: per-sample attn2 via hisenc . u_p ----
    {
      int b = blk;
      for (int d = tid; d < 512; d += 256) h_s[d] = u_p[(size_t)b * 512 + d];
      __syncthreads();
      {
        int l = tid >> 1, part = tid & 1;
        const u16* row = hisenc + ((size_t)b * 128 + l) * 512 + part * 256;
        float s = 0.f;
        for (int k = 0; k < 256; k += 8) {
          bf16x8 v = load8(row + k);
#pragma unroll
          for (int e = 0; e < 8; e++) s += bf2f((u16)v[e]) * h_s[part * 256 + k + e];
        }
        red[tid] = s;
      }
      __syncthreads();
      float sc = (tid < 128) ? red[tid * 2] + red[tid * 2 + 1] : 0.f;
      __syncthreads();
      if (tid < 128) red[tid] = sc;
      __syncthreads();
      if (tid < 64) {
        float m = fmaxf(red[tid], red[tid + 64]);
        for (int off = 32; off > 0; off >>= 1) m = fmaxf(m, __shfl_xor(m, off));
        if (tid == 0) mr[0] = m;
      }
      __syncthreads();
      float ex = 0.f;
      if (tid < 128) { ex = __expf(sc - mr[0]); red[tid] = ex; }
      __syncthreads();
      if (tid < 64) {
        float s2 = red[tid] + red[tid + 64];
        for (int off = 32; off > 0; off >>= 1) s2 += __shfl_xor(s2, off);
        if (tid == 0) mr[1] = s2;
      }
      __syncthreads();
      if (tid < 128) aw[tid] = ex / mr[1];
      __syncthreads();
      for (int d = tid; d < 512; d += 256) {
        float z = 0.f;
        for (int l = 0; l < 128; l++) z += aw[l] * bf2f(hisenc[((size_t)b * 128 + l) * 512 + d]);
        qattn[(size_t)b * 1024 + 512 + d] = f2bf(z);
      }
    }
    gbar(bar, 128);

    // ---- Phase 4: hk GEMM (16 blocks) ----
    if (blk < 16) {
      int m0 = (blk & 1) * 64 + (wave >> 1) * 32;
      int n0 = (blk >> 1) * 64 + (wave & 1) * 32;
      f32x4 acc[2][2] = {};
      const u16* pA[2]; const u16* pB[2];
#pragma unroll
      for (int i = 0; i < 2; i++) {
        pA[i] = qattn + (size_t)(m0 + i * 16 + col) * 1024 + q * 8;
        pB[i] = wbd01_bf + (size_t)(n0 + i * 16 + col) * 1024 + q * 8;
      }
      for (int k = 0; k < 1024; k += 32) {
        bf16x8 a0 = load8(pA[0] + k), a1 = load8(pA[1] + k);
        bf16x8 b0 = load8(pB[0] + k), b1 = load8(pB[1] + k);
        acc[0][0] = __builtin_amdgcn_mfma_f32_16x16x32_bf16(a0, b0, acc[0][0], 0, 0, 0);
        acc[0][1] = __builtin_amdgcn_mfma_f32_16x16x32_bf16(a0, b1, acc[0][1], 0, 0, 0);
        acc[1][0] = __builtin_amdgcn_mfma_f32_16x16x32_bf16(a1, b0, acc[1][0], 0, 0, 0);
        acc[1][1] = __builtin_amdgcn_mfma_f32_16x16x32_bf16(a1, b1, acc[1][1], 0, 0, 0);
      }
#pragma unroll
      for (int mi = 0; mi < 2; mi++)
#pragma unroll
        for (int ni = 0; ni < 2; ni++)
#pragma unroll
          for (int r = 0; r < 4; r++) {
            int m = m0 + mi * 16 + q * 4 + r;
            int n = n0 + ni * 16 + col;
            int act = clampi(actions[m * 32 + t], 0, 99);
            float v = acc[mi][ni][r] + hkbase[m * 512 + n] + projact[(size_t)act * 512 + n];
            zin_cur[(size_t)m * 1024 + n] = f2bf(tanhf(v));
          }
    }
    gbar(bar, 128);

    // ---- Phase 5: gates GEMM + cell (64 blocks) ----
    if (blk < 64) {
      int bx = blk & 1, by = blk >> 1;  // by 0..31
      int m0 = bx * 64 + (wave >> 1) * 32;
      int n0 = by * 64 + (wave & 1) * 32;
      f32x4 acc[2][2] = {};
      const u16* pA[2]; const u16* pI[2]; const u16* pH[2];
#pragma unroll
      for (int i = 0; i < 2; i++) {
        pA[i] = zin_cur + (size_t)(m0 + i * 16 + col) * 1024 + q * 8;
        int rr = n0 + i * 16 + col;
        int src = (rr & 3) * 512 + (rr >> 2);
        pI[i] = dwih_bf + (size_t)src * 512 + q * 8;
        pH[i] = dwhh_bf + (size_t)src * 512 + q * 8;
      }
      for (int k = 0; k < 512; k += 32) {
        bf16x8 a0 = load8(pA[0] + k), a1 = load8(pA[1] + k);
        bf16x8 b0 = load8(pI[0] + k), b1 = load8(pI[1] + k);
        acc[0][0] = __builtin_amdgcn_mfma_f32_16x16x32_bf16(a0, b0, acc[0][0], 0, 0, 0);
        acc[0][1] = __builtin_amdgcn_mfma_f32_16x16x32_bf16(a0, b1, acc[0][1], 0, 0, 0);
        acc[1][0] = __builtin_amdgcn_mfma_f32_16x16x32_bf16(a1, b0, acc[1][0], 0, 0, 0);
        acc[1][1] = __builtin_amdgcn_mfma_f32_16x16x32_bf16(a1, b1, acc[1][1], 0, 0, 0);
      }
      for (int k = 0; k < 512; k += 32) {
        bf16x8 a0 = load8(pA[0] + 512 + k), a1 = load8(pA[1] + 512 + k);
        bf16x8 b0 = load8(pH[0] + k), b1 = load8(pH[1] + k);
        acc[0][0] = __builtin_amdgcn_mfma_f32_16x16x32_bf16(a0, b0, acc[0][0], 0, 0, 0);
        acc[0][1] = __builtin_amdgcn_mfma_f32_16x16x32_bf16(a0, b1, acc[0][1], 0, 0, 0);
        acc[1][0] = __builtin_amdgcn_mfma_f32_16x16x32_bf16(a1, b0, acc[1][0], 0, 0, 0);
        acc[1][1] = __builtin_amdgcn_mfma_f32_16x16x32_bf16(a1, b1, acc[1][1], 0, 0, 0);
      }
      float (*ls)[68] = (float(*)[68])smem;
      __syncthreads();
#pragma unroll
      for (int mi = 0; mi < 2; mi++)
#pragma unroll
        for (int ni = 0; ni < 2; ni++)
#pragma unroll
          for (int r = 0; r < 4; r++) {
            int nl = (wave & 1) * 32 + ni * 16 + col;
            int ml = (wave >> 1) * 32 + mi * 16 + q * 4 + r;
            ls[ml][nl] = acc[mi][ni][r] + bdecint[by * 64 + nl];
          }
      __syncthreads();
      int m = tid & 63, grp = tid >> 6;
      int gm = bx * 64 + m;
      int j0 = by * 16;
#pragma unroll
      for (int jl = 0; jl < 4; jl++) {
        int jc = grp * 4 + jl;
        float gi = ls[m][jc * 4 + 0], gf = ls[m][jc * 4 + 1];
        float gg = ls[m][jc * 4 + 2], go = ls[m][jc * 4 + 3];
        int j = j0 + jc;
        float cold = (t == 0) ? c0[gm * 512 + j] : creg[jl];
        float cn = sigf(gf) * cold + sigf(gi) * tanhf(gg);
        creg[jl] = cn;
        u16 hb = f2bf(sigf(go) * tanhf(cn));
        zin_nxt[(size_t)gm * 1024 + 512 + j] = hb;
        qbuf[(size_t)gm * 1024 + j] = hb;
        outs[((size_t)gm * 32 + t) * 512 + j] = hb;
      }
    }
    gbar(bar, 128);
  }

  // ---- logits tail: 128 blocks cover (4096 x 100), K=512 ----
  {
    int m0 = (blk >> 1) * 64 + (wave >> 1) * 32;
    int n0 = (blk & 1) * 64 + (wave & 1) * 32;
    f32x4 acc[2][2] = {};
    int rB[2] = { n0 + col, n0 + 16 + col };
    bool gB[2] = { rB[0] < 100, rB[1] < 100 };
    const u16* pA[2]; const u16* pB[2];
#pragma unroll
    for (int i = 0; i < 2; i++) {
      pA[i] = outs + (size_t)(m0 + i * 16 + col) * 512 + q * 8;
      pB[i] = h2a_bf + (size_t)(gB[i] ? rB[i] : 0) * 512 + q * 8;
    }
    bf16x8 zf = {0,0,0,0,0,0,0,0};
    for (int k = 0; k < 512; k += 32) {
      bf16x8 a0 = load8(pA[0] + k), a1 = load8(pA[1] + k);
      bf16x8 b0 = gB[0] ? load8(pB[0] + k) : zf;
      bf16x8 b1 = gB[1] ? load8(pB[1] + k) : zf;
      acc[0][0] = __builtin_amdgcn_mfma_f32_16x16x32_bf16(a0, b0, acc[0][0], 0, 0, 0);
      acc[0][1] = __builtin_amdgcn_mfma_f32_16x16x32_bf16(a0, b1, acc[0][1], 0, 0, 0);
      acc[1][0] = __builtin_amdgcn_mfma_f32_16x16x32_bf16(a1, b0, acc[1][0], 0, 0, 0);
      acc[1][1] = __builtin_amdgcn_mfma_f32_16x16x32_bf16(a1, b1, acc[1][1], 0, 0, 0);
    }
#pragma unroll
    for (int mi = 0; mi < 2; mi++)
#pragma unroll
      for (int ni = 0; ni < 2; ni++)
#pragma unroll
        for (int r = 0; r < 4; r++) {
          int m = m0 + mi * 16 + q * 4 + r;
          int n = n0 + ni * 16 + col;
          if (n < 100) logits[(size_t)m * 100 + n] = acc[mi][ni][r] + bh2a[n];
        }
  }
}

// ---------------------------------------------------------------------------
extern "C" void kernel_launch(void* const* d_in, const int* in_sizes, int n_in,
                              void* d_out, int out_size, void* d_ws, size_t ws_size,
                              hipStream_t stream) {
  const int* ins_tok = (const int*)d_in[0];
  const int* his_tok = (const int*)d_in[1];
  const int* actions = (const int*)d_in[2];
  const int* cur_env = (const int*)d_in[3];
  const int* ini_env = (const int*)d_in[4];
  const float* enc_emb = (const float*)d_in[5];
  const float* Wih_f = (const float*)d_in[6];
  const float* Whh_f = (const float*)d_in[7];
  const float* bih_f = (const float*)d_in[8];
  const float* bhh_f = (const float*)d_in[9];
  const float* Wih_b = (const float*)d_in[10];
  const float* Whh_b = (const float*)d_in[11];
  const float* bih_b = (const float*)d_in[12];
  const float* bhh_b = (const float*)d_in[13];
  const float* color_emb = (const float*)d_in[14];
  const float* pos_emb = (const float*)d_in[15];
  const float* ws_Wih = (const float*)d_in[16];
  const float* ws_Whh = (const float*)d_in[17];
  const float* ws_bih = (const float*)d_in[18];
  const float* ws_bhh = (const float*)d_in[19];
  const float* act_emb = (const float*)d_in[20];
  const float* W_c = (const float*)d_in[21];
  const float* W_p = (const float*)d_in[22];
  const float* Wbd_W = (const float*)d_in[27];
  const float* Wbd_b = (const float*)d_in[28];
  const float* dec_Wih = (const float*)d_in[29];
  const float* dec_Whh = (const float*)d_in[30];
  const float* dec_bih = (const float*)d_in[31];
  const float* dec_bhh = (const float*)d_in[32];
  const float* h2a_W = (const float*)d_in[33];
  const float* h2a_b = (const float*)d_in[34];
  const float* h0 = (const float*)d_in[35];
  const float* c0 = (const float*)d_in[36];
  (void)in_sizes; (void)n_in; (void)out_size; (void)ws_size;

  char* ws = (char*)d_ws;
  size_t off = 0;
  auto alloc = [&](size_t bytes) -> char* {
    char* p = ws + off;
    off = (off + bytes + 255) & ~(size_t)255;
    return p;
  };
  u16* insenc   = (u16*)alloc(8192ull * 512 * 2);
  u16* hisenc   = (u16*)alloc(16384ull * 512 * 2);
  u16* outs     = (u16*)alloc(4096ull * 512 * 2);
  u16* A_c      = (u16*)alloc(8192ull * 512 * 2);
  u16* Wsum     = (u16*)alloc(512ull * 896 * 2);
  u16* h_enc    = (u16*)alloc(2 * HBUF * 2);
  float* projact= (float*)alloc(100ull * 512 * 4);
  float* bias_f = (float*)alloc(1024 * 4);
  float* bias_b = (float*)alloc(1024 * 4);
  float* bdecint= (float*)alloc(2048 * 4);
  float* bwbd   = (float*)alloc(512 * 4);
  float* bh2a   = (float*)alloc(128 * 4);
  u16* ctxcat   = (u16*)alloc(128ull * 896 * 2);
  float* hkbase = (float*)alloc(128ull * 512 * 4);
  float* u_p    = (float*)alloc(128ull * 512 * 4);
  u16* qbuf     = (u16*)alloc(128ull * 1024 * 2);
  u16* qattn    = (u16*)alloc(128ull * 1024 * 2);
  u16* zin      = (u16*)alloc(2ull * 128 * 1024 * 2);
  int* bars     = (int*)alloc(1024 * 4);
  u16* emb_bf   = (u16*)alloc(2000ull * 128 * 2);
  u16* wihf_bf  = (u16*)alloc(1024ull * 128 * 2);
  u16* wihb_bf  = (u16*)alloc(1024ull * 128 * 2);
  u16* whhf_bf  = (u16*)alloc(1024ull * 256 * 2);
  u16* whhb_bf  = (u16*)alloc(1024ull * 256 * 2);
  u16* act_bf   = (u16*)alloc(100ull * 128 * 2);
  u16* wp_bf    = (u16*)alloc(512ull * 1024 * 2);
  u16* wbd01_bf = (u16*)alloc(512ull * 1024 * 2);
  u16* wbdx_bf  = (u16*)alloc(512ull * 128 * 2);
  u16* dwih_bf  = (u16*)alloc(2048ull * 512 * 2);
  u16* dwhh_bf  = (u16*)alloc(2048ull * 512 * 2);
  u16* h2a_bf   = (u16*)alloc(100ull * 512 * 2);
  u16* wcT_bf   = (u16*)alloc(512ull * 512 * 2);

  bar_init<<<1, 256, 0, stream>>>(bars);

  // fused weight conversion
  CvtAll ca{};
  const float* srcs[12] = {enc_emb, Wih_f, Wih_b, Whh_f, Whh_b, act_emb,
                           W_p, Wbd_W, Wbd_W, dec_Wih, dec_Whh, h2a_W};
  u16* dsts[12] = {emb_bf, wihf_bf, wihb_bf, whhf_bf, whhb_bf, act_bf,
                   wp_bf, wbd01_bf, wbdx_bf, dwih_bf, dwhh_bf, h2a_bf};
  int Rs[12] = {2000, 1024, 1024, 1024, 1024, 100, 512, 512, 512, 2048, 2048, 100};
  int Cs[12] = {128, 128, 128, 256, 256, 128, 1024, 1024, 128, 512, 512, 512};
  int lds[12] = {128, 128, 128, 256, 256, 128, 1024, 2944, 2944, 512, 512, 512};
  int c0s[12] = {0, 0, 0, 0, 0, 0, 0, 0, 2816, 0, 0, 0};
  int blkacc = 0;
  for (int s = 0; s < 12; s++) {
    ca.src[s] = srcs[s]; ca.dst[s] = dsts[s];
    ca.R[s] = Rs[s]; ca.C[s] = Cs[s]; ca.ld[s] = lds[s]; ca.c0[s] = c0s[s];
    ca.blk0[s] = blkacc;
    blkacc += (Rs[s] * Cs[s] + 255) / 256;
  }
  ca.blk0[12] = blkacc;
  cvt_all_k<<<blkacc, 256, 0, stream>>>(ca);
  cvt_T<<<1024, 256, 0, stream>>>(W_c, wcT_bf);
  smallprep<<<19, 256, 0, stream>>>(bih_f, bhh_f, bih_b, bhh_b, Wbd_b, h2a_b,
                                    dec_bih, dec_bhh, bias_f, bias_b, bwbd, bh2a, bdecint);
  wsum_build<<<1792, 256, 0, stream>>>(Wbd_W, Wsum);

  env_encode<<<224, 256, 0, stream>>>(cur_env, ini_env, color_emb, pos_emb,
                                      ws_Wih, ws_Whh, ws_bih, ws_bhh, ctxcat);

  GemmArgs gp = {act_bf, 128, 100, wbdx_bf, 128, 512, 128, projact, 512, bwbd};
  gemm_k<0><<<dim3(2, 8), 256, 0, stream>>>(gp);
  GemmArgs gb = {ctxcat, 896, 128, Wsum, 896, 512, 896, hkbase, 512, nullptr};
  gemm_k<0><<<dim3(2, 8), 256, 0, stream>>>(gb);

  enc_persist<<<128, 256, 0, stream>>>(ins_tok, his_tok, emb_bf, wihf_bf, wihb_bf,
                                       whhf_bf, whhb_bf, bias_f, bias_b,
                                       h_enc, insenc, hisenc, bars);

  GemmArgs gc = {insenc, 512, 8192, wcT_bf, 512, 512, 512, A_c, 512, nullptr};
  gemm_k<1><<<dim3(128, 8), 256, 0, stream>>>(gc);

  dec_persist<<<128, 256, 0, stream>>>(A_c, insenc, hisenc, wp_bf, wbd01_bf,
                                       dwih_bf, dwhh_bf, bdecint, hkbase, projact,
                                       actions, h0, c0, u_p, qbuf, qattn, zin, outs,
                                       h2a_bf, bh2a, (float*)d_out, bars + 512);
}

// Round 6
// 6502.200 us; speedup vs baseline: 1.3235x; 1.3235x over previous
//
#include <hip/hip_runtime.h>

// Seq2Seq round 6: fence-free persistent decoder (LLC-mediated state, L2 stays
// warm) + barrier-free block-local encoder. f32 inputs, bf16 MFMA pipeline.

typedef unsigned short u16;
typedef unsigned long long u64;
typedef __attribute__((ext_vector_type(8))) short bf16x8;
typedef __attribute__((ext_vector_type(4))) float f32x4;

#define DEVFN static __device__ __forceinline__

DEVFN float bf2f(u16 u) {
  unsigned int x = ((unsigned int)u) << 16;
  float f; __builtin_memcpy(&f, &x, 4); return f;
}
DEVFN u16 f2bf(float f) {
  unsigned int x; __builtin_memcpy(&x, &f, 4);
  x = (x + 0x7fffu + ((x >> 16) & 1u)) >> 16;
  return (u16)x;
}
DEVFN float sigf(float x) { return 1.f / (1.f + __expf(-x)); }
DEVFN bf16x8 load8(const u16* p) { return *(const bf16x8*)p; }
DEVFN int clampi(int v, int lo, int hi) { return v < lo ? lo : (v > hi ? hi : v); }

// ---- agent-scope (sc1, LLC-direct) accessors for cross-block mutable state ----
DEVFN u64 ald64(const u16* p) {
  return __hip_atomic_load((u64*)p, __ATOMIC_RELAXED, __HIP_MEMORY_SCOPE_AGENT);
}
DEVFN void ast64(u16* p, u64 v) {
  __hip_atomic_store((u64*)p, v, __ATOMIC_RELAXED, __HIP_MEMORY_SCOPE_AGENT);
}
DEVFN void ast32(void* p, unsigned v) {
  __hip_atomic_store((unsigned*)p, v, __ATOMIC_RELAXED, __HIP_MEMORY_SCOPE_AGENT);
}
DEVFN bf16x8 load8_sc(const u16* p) {
  u64 v[2] = { ald64(p), ald64(p + 4) };
  bf16x8 r; __builtin_memcpy(&r, v, 16); return r;
}
DEVFN u64 pack4(float a, float b, float c, float d) {
  return (u64)f2bf(a) | ((u64)f2bf(b) << 16) | ((u64)f2bf(c) << 32) | ((u64)f2bf(d) << 48);
}
DEVFN unsigned pack2(float a, float b) {
  return (unsigned)f2bf(a) | ((unsigned)f2bf(b) << 16);
}
DEVFN float u64bf(u64 v, int i) { return bf2f((u16)(v >> (16 * i))); }

// Fence-free device barrier: monotonic LLC counter, no L2 writeback/invalidate.
DEVFN void gbar(int* bar, int expected) {
  __syncthreads();  // per-wave vmcnt(0) drain before s_barrier: all stores at LLC
  if (threadIdx.x == 0) {
    __builtin_amdgcn_s_waitcnt(0);
    __hip_atomic_fetch_add(bar, 1, __ATOMIC_RELAXED, __HIP_MEMORY_SCOPE_AGENT);
    while (__hip_atomic_load(bar, __ATOMIC_RELAXED, __HIP_MEMORY_SCOPE_AGENT) < expected)
      __builtin_amdgcn_s_sleep(1);
  }
  __syncthreads();
}

// ---------------------------------------------------------------------------
// Generic MFMA GEMM: out[m,n] = sum_k A[m,k]*W[n,k]. EPI 0: f32 (+bias). 1: bf16.
// ---------------------------------------------------------------------------
struct GemmArgs {
  const u16* A; int lda; int M;
  const u16* W; int ldw; int N; int K;
  void* out; int ldc;
  const float* bias;
};

template <int EPI>
__global__ __launch_bounds__(256) void gemm_k(GemmArgs g) {
  int lane = threadIdx.x & 63, wave = threadIdx.x >> 6;
  int col = lane & 15, q = lane >> 4;
  int m0 = blockIdx.x * 64 + (wave >> 1) * 32;
  int n0 = blockIdx.y * 64 + (wave & 1) * 32;
  f32x4 acc[2][2] = {};
  int rA[2] = { m0 + col, m0 + 16 + col };
  int rB[2] = { n0 + col, n0 + 16 + col };
  bool gA[2] = { rA[0] < g.M, rA[1] < g.M };
  bool gB[2] = { rB[0] < g.N, rB[1] < g.N };
  const u16* pA[2]; const u16* pB[2];
#pragma unroll
  for (int i = 0; i < 2; i++) {
    pA[i] = g.A + (size_t)(gA[i] ? rA[i] : 0) * g.lda + q * 8;
    pB[i] = g.W + (size_t)(gB[i] ? rB[i] : 0) * g.ldw + q * 8;
  }
  bf16x8 zf = {0,0,0,0,0,0,0,0};
  for (int k = 0; k < g.K; k += 32) {
    bf16x8 a0 = gA[0] ? load8(pA[0] + k) : zf;
    bf16x8 a1 = gA[1] ? load8(pA[1] + k) : zf;
    bf16x8 b0 = gB[0] ? load8(pB[0] + k) : zf;
    bf16x8 b1 = gB[1] ? load8(pB[1] + k) : zf;
    acc[0][0] = __builtin_amdgcn_mfma_f32_16x16x32_bf16(a0, b0, acc[0][0], 0, 0, 0);
    acc[0][1] = __builtin_amdgcn_mfma_f32_16x16x32_bf16(a0, b1, acc[0][1], 0, 0, 0);
    acc[1][0] = __builtin_amdgcn_mfma_f32_16x16x32_bf16(a1, b0, acc[1][0], 0, 0, 0);
    acc[1][1] = __builtin_amdgcn_mfma_f32_16x16x32_bf16(a1, b1, acc[1][1], 0, 0, 0);
  }
#pragma unroll
  for (int mi = 0; mi < 2; mi++)
#pragma unroll
    for (int ni = 0; ni < 2; ni++)
#pragma unroll
      for (int r = 0; r < 4; r++) {
        int m = m0 + mi * 16 + q * 4 + r;
        int n = n0 + ni * 16 + col;
        if (m >= g.M || n >= g.N) continue;
        float v = acc[mi][ni][r];
        if (g.bias) v += g.bias[n];
        if constexpr (EPI == 0) ((float*)g.out)[(size_t)m * g.ldc + n] = v;
        else ((u16*)g.out)[(size_t)m * g.ldc + n] = f2bf(v);
      }
}

// ---------------------------------------------------------------------------
// prep kernels
// ---------------------------------------------------------------------------
struct CvtAll {
  const float* src[12]; u16* dst[12];
  int R[12], C[12], ld[12], c0[12], mode[12], blk0[13];
};
__global__ __launch_bounds__(256) void cvt_all_k(CvtAll a) {
  int blk = blockIdx.x, s = 0;
  while (s < 11 && blk >= a.blk0[s + 1]) s++;
  int idx = (blk - a.blk0[s]) * 256 + threadIdx.x;
  int n = a.R[s] * a.C[s];
  if (idx >= n) return;
  int r = idx / a.C[s], c = idx - r * a.C[s];
  int sr = (a.mode[s] == 1) ? ((r & 3) * 256 + (r >> 2)) : r;  // gate interleave
  a.dst[s][idx] = f2bf(a.src[s][(size_t)sr * a.ld[s] + a.c0[s] + c]);
}

// wcT[k*512+d] = bf16(W_c[d*512+k])
__global__ void cvt_T(const float* in, u16* out) {
  int idx = blockIdx.x * 256 + threadIdx.x;
  int n = idx >> 9, d = idx & 511;
  out[idx] = f2bf(in[(size_t)d * 512 + n]);
}

__global__ void smallprep(const float* bihf, const float* bhhf, const float* bihb, const float* bhhb,
                          const float* Wbdb, const float* h2ab, const float* dbih, const float* dbhh,
                          float* bias_f, float* bias_b, float* bwbd, float* bh2a, float* bdecint,
                          int* bars) {
  int i = blockIdx.x * 256 + threadIdx.x;
  if (i < 1024) { int src = (i & 3) * 256 + (i >> 2); bias_f[i] = bihf[src] + bhhf[src]; }
  else if (i < 2048) { int r = i - 1024; int src = (r & 3) * 256 + (r >> 2); bias_b[r] = bihb[src] + bhhb[src]; }
  else if (i < 2560) { int k = i - 2048; bwbd[k] = Wbdb[k]; }
  else if (i < 2660) { int k = i - 2560; bh2a[k] = h2ab[k]; }
  else if (i < 4708) { int r = i - 2660; int j = r >> 2, gg = r & 3; bdecint[r] = dbih[gg * 512 + j] + dbhh[gg * 512 + j]; }
  else if (i < 4724) bars[i - 4708] = 0;
}

__global__ void wsum_build(const float* Wbd, u16* Wsum) {
  int idx = blockIdx.x * 256 + threadIdx.x;  // 512*896
  int n = idx / 896, j = idx % 896;
  int c1 = (j < 448) ? (1024 + j) : (1920 + (j - 448));
  int c2 = c1 + 448;
  Wsum[idx] = f2bf(Wbd[(size_t)n * 2944 + c1] + Wbd[(size_t)n * 2944 + c2]);
}

// ---------------------------------------------------------------------------
// Env encoder: 1792 4-step LSTM chains (hidden 32) -> ctx_cat(B,896) bf16
// ---------------------------------------------------------------------------
__global__ __launch_bounds__(256) void env_encode(
    const int* cur_env, const int* ini_env,
    const float* color_emb, const float* pos_emb,
    const float* wih, const float* whh, const float* bih, const float* bhh,
    u16* ctx_cat) {
  __shared__ float s_wih[128 * 33], s_whh[128 * 33], s_b[128], s_col[7 * 32];
  __shared__ float h_lds[8][33];
  int tid = threadIdx.x;
  for (int i = tid; i < 128 * 32; i += 256) {
    int r = i >> 5, k2 = i & 31;
    s_wih[r * 33 + k2] = wih[i];
    s_whh[r * 33 + k2] = whh[i];
  }
  for (int i = tid; i < 128; i += 256) s_b[i] = bih[i] + bhh[i];
  for (int i = tid; i < 224; i += 256) s_col[i] = color_emb[i];
  int sl = tid >> 5, j = tid & 31;
  int gseq = blockIdx.x * 8 + sl;
  int e = gseq / 896, rem = gseq % 896;
  int b = rem / 7, p = rem % 7;
  const int* env = e ? ini_env : cur_env;
  int eoff = e ? 0 : 448;
  h_lds[sl][j] = 0.f;
  __syncthreads();
  float cj = 0.f, hj = 0.f;
  for (int st = 0; st < 4; st++) {
    int tok = clampi(env[b * 35 + p * 5 + 1 + st], 0, 6);
    const float* x = &s_col[tok * 32];
    float pi = s_b[j], pf = s_b[32 + j], pg = s_b[64 + j], po = s_b[96 + j];
    for (int k = 0; k < 32; k++) {
      float xk = x[k], hk = h_lds[sl][k];
      pi += s_wih[j * 33 + k] * xk + s_whh[j * 33 + k] * hk;
      pf += s_wih[(32 + j) * 33 + k] * xk + s_whh[(32 + j) * 33 + k] * hk;
      pg += s_wih[(64 + j) * 33 + k] * xk + s_whh[(64 + j) * 33 + k] * hk;
      po += s_wih[(96 + j) * 33 + k] * xk + s_whh[(96 + j) * 33 + k] * hk;
    }
    cj = sigf(pf) * cj + sigf(pi) * tanhf(pg);
    hj = sigf(po) * tanhf(cj);
    __syncthreads();
    h_lds[sl][j] = hj;
    __syncthreads();
  }
  size_t base = (size_t)b * 896 + eoff + p * 64;
  ctx_cat[base + j] = f2bf(pos_emb[p * 32 + j]);
  ctx_cat[base + 32 + j] = f2bf(hj);
}

// ---------------------------------------------------------------------------
// Block-local persistent encoder: 32 blocks x 1024 thr. Block = (chain, 16
// samples). h in LDS, c in regs, gate-interleaved weights, proj table for x.
// No inter-block communication at all.
// ---------------------------------------------------------------------------
__global__ __launch_bounds__(1024) void enc_persist(
    const int* ins_tok, const int* his_tok,
    const u16* whhf_int, const u16* whhb_int,
    const u16* projf, const u16* projb,
    u16* ins_enc, u16* his_enc) {
  int blk = blockIdx.x;
  int chain = blk >> 3, sgrp = blk & 7;
  int dir = chain & 1, his = chain >> 1;
  int L = his ? 128 : 64;
  const int* toks = his ? his_tok : ins_tok;
  const u16* whh = dir ? whhb_int : whhf_int;
  const u16* proj = dir ? projb : projf;
  u16* out = his ? his_enc : ins_enc;
  int tid = threadIdx.x;
  int wv = tid >> 6, lane = tid & 63, col = lane & 15, q = lane >> 4;
  __shared__ u16 s_h[16][264];
  __shared__ float s_st[16][16][4][17];  // [wave][sample][tile][nl]
  __shared__ int s_tok[16];
  const u16* pB[4];
#pragma unroll
  for (int nt = 0; nt < 4; nt++)
    pB[nt] = whh + (size_t)(wv * 64 + nt * 16 + col) * 256 + q * 8;
  float c4[4] = {0.f, 0.f, 0.f, 0.f};
  int sm = lane & 15, jl = lane >> 4;
  for (int t = 0; t < L; t++) {
    int t_x = dir ? (L - 1 - t) : t;
    if (tid < 16) s_tok[tid] = clampi(toks[(sgrp * 16 + tid) * L + t_x], 0, 1999);
    __syncthreads();
    f32x4 acc[4] = {};
    if (t > 0) {
      bf16x8 af[8];
#pragma unroll
      for (int kt = 0; kt < 8; kt++)
        af[kt] = *(const bf16x8*)&s_h[col][kt * 32 + q * 8];
#pragma unroll
      for (int kt = 0; kt < 8; kt++)
#pragma unroll
        for (int nt = 0; nt < 4; nt++)
          acc[nt] = __builtin_amdgcn_mfma_f32_16x16x32_bf16(af[kt], load8(pB[nt] + kt * 32), acc[nt], 0, 0, 0);
    }
#pragma unroll
    for (int nt = 0; nt < 4; nt++)
#pragma unroll
      for (int r = 0; r < 4; r++)
        s_st[wv][q * 4 + r][nt][col] = acc[nt][r];
    __syncthreads();  // MFMA reads of s_h done; staging visible
    int tokv = s_tok[sm];
    const u16* prow = proj + (size_t)tokv * 1024;
#pragma unroll
    for (int nt = 0; nt < 4; nt++) {
      int j = wv * 16 + nt * 4 + jl;
      const u16* pp = prow + j * 4;
      float gi = s_st[wv][sm][nt][jl * 4 + 0] + bf2f(pp[0]);
      float gf = s_st[wv][sm][nt][jl * 4 + 1] + bf2f(pp[1]);
      float gg = s_st[wv][sm][nt][jl * 4 + 2] + bf2f(pp[2]);
      float go = s_st[wv][sm][nt][jl * 4 + 3] + bf2f(pp[3]);
      float cn = sigf(gf) * c4[nt] + sigf(gi) * tanhf(gg);
      c4[nt] = cn;
      u16 hb = f2bf(sigf(go) * tanhf(cn));
      s_h[sm][j] = hb;
      out[((size_t)(sgrp * 16 + sm) * L + t_x) * 512 + dir * 256 + j] = hb;
    }
    // next-iteration top __syncthreads covers s_h writes before reads
  }
}

// ---------------------------------------------------------------------------
// Persistent decoder: 128 blocks x 256 thr, 32 steps x 5 phases, fence-free
// barriers. Mutable state (qbuf/u_p/qattn/zin) via sc1 atomics; read-only
// streams (A_c/insenc/hisenc/weights) stay L2-cached.
// ---------------------------------------------------------------------------
__global__ __launch_bounds__(256) void dec_persist(
    const u16* A_c, const u16* insenc, const u16* hisenc,
    const u16* wp_bf, const u16* wbd01_bf,
    const u16* dwih_bf, const u16* dwhh_bf,
    const float* bdecint, const float* hkbase, const float* projact,
    const int* actions, const float* h0, const float* c0,
    float* u_p, u16* qbuf, u16* qattn, u16* zin, u16* outs,
    int* bar) {
  int blk = blockIdx.x, tid = threadIdx.x;
  int lane = tid & 63, wave = tid >> 6, col = lane & 15, q = lane >> 4;
  __shared__ float smem[64 * 68];
  float* h_s = smem;        // 512
  float* red = smem + 512;  // 256
  float* aw  = smem + 768;  // 128
  float* mr  = smem + 896;  // 2
  float creg[4] = {0.f, 0.f, 0.f, 0.f};
  int bcnt = 0;

  // init own sample's h into zin/qbuf (sc1)
  {
    int d0 = tid * 2;
    unsigned pv = pack2(h0[blk * 512 + d0], h0[blk * 512 + d0 + 1]);
    ast32(zin + (size_t)blk * 1024 + 512 + d0, pv);
    ast32(qbuf + (size_t)blk * 1024 + d0, pv);
  }
  __syncthreads();

  for (int t = 0; t < 32; t++) {
    u16* zin_cur = zin + (size_t)(t & 1) * 131072;
    u16* zin_nxt = zin + (size_t)((t + 1) & 1) * 131072;

    // ---- P1: attn1 (per-sample) ----
    {
      int b = blk;
      if (tid < 128) {
        u64 v = ald64(qbuf + (size_t)b * 1024 + tid * 4);
        h_s[tid * 4 + 0] = u64bf(v, 0);
        h_s[tid * 4 + 1] = u64bf(v, 1);
        h_s[tid * 4 + 2] = u64bf(v, 2);
        h_s[tid * 4 + 3] = u64bf(v, 3);
      }
      __syncthreads();
      {
        int l = tid >> 2, part = tid & 3;
        const u16* row = A_c + ((size_t)b * 64 + l) * 512 + part * 128;
        float s = 0.f;
        for (int k = 0; k < 128; k += 8) {
          bf16x8 v = load8(row + k);
#pragma unroll
          for (int e = 0; e < 8; e++) s += bf2f((u16)v[e]) * h_s[part * 128 + k + e];
        }
        red[tid] = s;
      }
      __syncthreads();
      if (tid < 64) {
        float sc = red[tid * 4] + red[tid * 4 + 1] + red[tid * 4 + 2] + red[tid * 4 + 3];
        float m = sc;
        for (int off = 32; off > 0; off >>= 1) m = fmaxf(m, __shfl_xor(m, off));
        float e = __expf(sc - m);
        float smv = e;
        for (int off = 32; off > 0; off >>= 1) smv += __shfl_xor(smv, off);
        aw[tid] = e / smv;
      }
      __syncthreads();
      int d0 = tid * 2;
      float z0 = 0.f, z1 = 0.f;
      const u16* zbase = insenc + (size_t)b * 64 * 512 + d0;
      for (int l = 0; l < 64; l++) {
        float a = aw[l];
        z0 += a * bf2f(zbase[l * 512]);
        z1 += a * bf2f(zbase[l * 512 + 1]);
      }
      unsigned pz = pack2(z0, z1);
      ast32(qattn + (size_t)b * 1024 + d0, pz);
      ast32(qbuf + (size_t)b * 1024 + 512 + d0, pz);
    }
    bcnt++; gbar(bar, 128 * bcnt);

    // ---- P2: u_p = [h|z_c] @ W_p^T (16 blocks) ----
    if (blk < 16) {
      int m0 = (blk & 1) * 64 + (wave >> 1) * 32;
      int n0 = (blk >> 1) * 64 + (wave & 1) * 32;
      f32x4 acc[2][2] = {};
      const u16* pA0 = qbuf + (size_t)(m0 + col) * 1024 + q * 8;
      const u16* pA1 = qbuf + (size_t)(m0 + 16 + col) * 1024 + q * 8;
      const u16* pB0 = wp_bf + (size_t)(n0 + col) * 1024 + q * 8;
      const u16* pB1 = wp_bf + (size_t)(n0 + 16 + col) * 1024 + q * 8;
      for (int k = 0; k < 1024; k += 32) {
        bf16x8 a0 = load8_sc(pA0 + k), a1 = load8_sc(pA1 + k);
        bf16x8 b0 = load8(pB0 + k), b1 = load8(pB1 + k);
        acc[0][0] = __builtin_amdgcn_mfma_f32_16x16x32_bf16(a0, b0, acc[0][0], 0, 0, 0);
        acc[0][1] = __builtin_amdgcn_mfma_f32_16x16x32_bf16(a0, b1, acc[0][1], 0, 0, 0);
        acc[1][0] = __builtin_amdgcn_mfma_f32_16x16x32_bf16(a1, b0, acc[1][0], 0, 0, 0);
        acc[1][1] = __builtin_amdgcn_mfma_f32_16x16x32_bf16(a1, b1, acc[1][1], 0, 0, 0);
      }
#pragma unroll
      for (int mi = 0; mi < 2; mi++)
#pragma unroll
        for (int ni = 0; ni < 2; ni++)
#pragma unroll
          for (int r = 0; r < 4; r++) {
            int m = m0 + mi * 16 + q * 4 + r, n = n0 + ni * 16 + col;
            float v = acc[mi][ni][r];
            unsigned uv; __builtin_memcpy(&uv, &v, 4);
            ast32(u_p + (size_t)m * 512 + n, uv);
          }
    }
    bcnt++; gbar(bar, 128 * bcnt);

    // ---- P3: attn2 (per-sample) ----
    {
      int b = blk;
      {
        u64 raw = __hip_atomic_load((u64*)(u_p + (size_t)b * 512 + tid * 2),
                                    __ATOMIC_RELAXED, __HIP_MEMORY_SCOPE_AGENT);
        float f2[2]; __builtin_memcpy(f2, &raw, 8);
        h_s[tid * 2] = f2[0]; h_s[tid * 2 + 1] = f2[1];
      }
      __syncthreads();
      {
        int l = tid >> 1, part = tid & 1;
        const u16* row = hisenc + ((size_t)b * 128 + l) * 512 + part * 256;
        float s = 0.f;
        for (int k = 0; k < 256; k += 8) {
          bf16x8 v = load8(row + k);
#pragma unroll
          for (int e = 0; e < 8; e++) s += bf2f((u16)v[e]) * h_s[part * 256 + k + e];
        }
        red[tid] = s;
      }
      __syncthreads();
      float sc = (tid < 128) ? red[tid * 2] + red[tid * 2 + 1] : 0.f;
      __syncthreads();
      if (tid < 128) red[tid] = sc;
      __syncthreads();
      if (tid < 64) {
        float m = fmaxf(red[tid], red[tid + 64]);
        for (int off = 32; off > 0; off >>= 1) m = fmaxf(m, __shfl_xor(m, off));
        if (tid == 0) mr[0] = m;
      }
      __syncthreads();
      float ex = 0.f;
      if (tid < 128) { ex = __expf(sc - mr[0]); red[tid] = ex; }
      __syncthreads();
      if (tid < 64) {
        float s2 = red[tid] + red[tid + 64];
        for (int off = 32; off > 0; off >>= 1) s2 += __shfl_xor(s2, off);
        if (tid == 0) mr[1] = s2;
      }
      __syncthreads();
      if (tid < 128) aw[tid] = ex / mr[1];
      __syncthreads();
      int d0 = tid * 2;
      float z0 = 0.f, z1 = 0.f;
      const u16* zbase = hisenc + (size_t)b * 128 * 512 + d0;
      for (int l = 0; l < 128; l++) {
        float a = aw[l];
        z0 += a * bf2f(zbase[l * 512]);
        z1 += a * bf2f(zbase[l * 512 + 1]);
      }
      ast32(qattn + (size_t)b * 1024 + 512 + d0, pack2(z0, z1));
    }
    bcnt++; gbar(bar, 128 * bcnt);

    // ---- P4: hk GEMM + tanh epilogue (16 blocks) ----
    if (blk < 16) {
      int m0b = (blk & 1) * 64, n0b = (blk >> 1) * 64;
      int m0 = m0b + (wave >> 1) * 32, n0 = n0b + (wave & 1) * 32;
      f32x4 acc[2][2] = {};
      const u16* pA0 = qattn + (size_t)(m0 + col) * 1024 + q * 8;
      const u16* pA1 = qattn + (size_t)(m0 + 16 + col) * 1024 + q * 8;
      const u16* pB0 = wbd01_bf + (size_t)(n0 + col) * 1024 + q * 8;
      const u16* pB1 = wbd01_bf + (size_t)(n0 + 16 + col) * 1024 + q * 8;
      for (int k = 0; k < 1024; k += 32) {
        bf16x8 a0 = load8_sc(pA0 + k), a1 = load8_sc(pA1 + k);
        bf16x8 b0 = load8(pB0 + k), b1 = load8(pB1 + k);
        acc[0][0] = __builtin_amdgcn_mfma_f32_16x16x32_bf16(a0, b0, acc[0][0], 0, 0, 0);
        acc[0][1] = __builtin_amdgcn_mfma_f32_16x16x32_bf16(a0, b1, acc[0][1], 0, 0, 0);
        acc[1][0] = __builtin_amdgcn_mfma_f32_16x16x32_bf16(a1, b0, acc[1][0], 0, 0, 0);
        acc[1][1] = __builtin_amdgcn_mfma_f32_16x16x32_bf16(a1, b1, acc[1][1], 0, 0, 0);
      }
      float (*ls)[68] = (float(*)[68])smem;
      __syncthreads();
#pragma unroll
      for (int mi = 0; mi < 2; mi++)
#pragma unroll
        for (int ni = 0; ni < 2; ni++)
#pragma unroll
          for (int r = 0; r < 4; r++)
            ls[(wave >> 1) * 32 + mi * 16 + q * 4 + r][(wave & 1) * 32 + ni * 16 + col] = acc[mi][ni][r];
      __syncthreads();
      for (int it = 0; it < 4; it++) {
        int idx = tid + it * 256;
        int ml = idx >> 4, nq = idx & 15, n = nq * 4;
        int gm = m0b + ml;
        int act = clampi(actions[gm * 32 + t], 0, 99);
        const float* hb_ = hkbase + (size_t)gm * 512 + n0b + n;
        const float* pa_ = projact + (size_t)act * 512 + n0b + n;
        float v0 = tanhf(ls[ml][n + 0] + hb_[0] + pa_[0]);
        float v1 = tanhf(ls[ml][n + 1] + hb_[1] + pa_[1]);
        float v2 = tanhf(ls[ml][n + 2] + hb_[2] + pa_[2]);
        float v3 = tanhf(ls[ml][n + 3] + hb_[3] + pa_[3]);
        ast64(zin_cur + (size_t)gm * 1024 + n0b + n, pack4(v0, v1, v2, v3));
      }
    }
    bcnt++; gbar(bar, 128 * bcnt);

    // ---- P5: gates GEMM + fused cell (64 blocks) ----
    if (blk < 64) {
      int bx = blk & 1, by = blk >> 1;
      int m0 = bx * 64 + (wave >> 1) * 32;
      int n0 = by * 64 + (wave & 1) * 32;
      f32x4 acc[2][2] = {};
      const u16* pA0 = zin_cur + (size_t)(m0 + col) * 1024 + q * 8;
      const u16* pA1 = zin_cur + (size_t)(m0 + 16 + col) * 1024 + q * 8;
      const u16* pI[2]; const u16* pH[2];
#pragma unroll
      for (int i = 0; i < 2; i++) {
        int rr = n0 + i * 16 + col;
        int src = (rr & 3) * 512 + (rr >> 2);
        pI[i] = dwih_bf + (size_t)src * 512 + q * 8;
        pH[i] = dwhh_bf + (size_t)src * 512 + q * 8;
      }
      for (int k = 0; k < 512; k += 32) {
        bf16x8 a0 = load8_sc(pA0 + k), a1 = load8_sc(pA1 + k);
        bf16x8 b0 = load8(pI[0] + k), b1 = load8(pI[1] + k);
        acc[0][0] = __builtin_amdgcn_mfma_f32_16x16x32_bf16(a0, b0, acc[0][0], 0, 0, 0);
        acc[0][1] = __builtin_amdgcn_mfma_f32_16x16x32_bf16(a0, b1, acc[0][1], 0, 0, 0);
        acc[1][0] = __builtin_amdgcn_mfma_f32_16x16x32_bf16(a1, b0, acc[1][0], 0, 0, 0);
        acc[1][1] = __builtin_amdgcn_mfma_f32_16x16x32_bf16(a1, b1, acc[1][1], 0, 0, 0);
      }
      for (int k = 0; k < 512; k += 32) {
        bf16x8 a0 = load8_sc(pA0 + 512 + k), a1 = load8_sc(pA1 + 512 + k);
        bf16x8 b0 = load8(pH[0] + k), b1 = load8(pH[1] + k);
        acc[0][0] = __builtin_amdgcn_mfma_f32_16x16x32_bf16(a0, b0, acc[0][0], 0, 0, 0);
        acc[0][1] = __builtin_amdgcn_mfma_f32_16x16x32_bf16(a0, b1, acc[0][1], 0, 0, 0);
        acc[1][0] = __builtin_amdgcn_mfma_f32_16x16x32_bf16(a1, b0, acc[1][0], 0, 0, 0);
        acc[1][1] = __builtin_amdgcn_mfma_f32_16x16x32_bf16(a1, b1, acc[1][1], 0, 0, 0);
      }
      float (*ls)[68] = (float(*)[68])smem;
      __syncthreads();
#pragma unroll
      for (int mi = 0; mi < 2; mi++)
#pragma unroll
        for (int ni = 0; ni < 2; ni++)
#pragma unroll
          for (int r = 0; r < 4; r++) {
            int nl = (wave & 1) * 32 + ni * 16 + col;
            int ml = (wave >> 1) * 32 + mi * 16 + q * 4 + r;
            ls[ml][nl] = acc[mi][ni][r] + bdecint[by * 64 + nl];
          }
      __syncthreads();
      int m = tid & 63, grp = tid >> 6;
      int gm = bx * 64 + m;
      int j0 = by * 16 + grp * 4;
      float hv[4];
#pragma unroll
      for (int jl = 0; jl < 4; jl++) {
        int jc = grp * 4 + jl;
        float gi = ls[m][jc * 4 + 0], gf = ls[m][jc * 4 + 1];
        float gg = ls[m][jc * 4 + 2], go = ls[m][jc * 4 + 3];
        int j = by * 16 + jc;
        float cold = (t == 0) ? c0[(size_t)gm * 512 + j] : creg[jl];
        float cn = sigf(gf) * cold + sigf(gi) * tanhf(gg);
        creg[jl] = cn;
        hv[jl] = sigf(go) * tanhf(cn);
      }
      u64 ph = pack4(hv[0], hv[1], hv[2], hv[3]);
      ast64(zin_nxt + (size_t)gm * 1024 + 512 + j0, ph);
      ast64(qbuf + (size_t)gm * 1024 + j0, ph);
      *(u64*)(outs + ((size_t)gm * 32 + t) * 512 + j0) = ph;  // normal store
    }
    bcnt++; gbar(bar, 128 * bcnt);
  }
}

// ---------------------------------------------------------------------------
extern "C" void kernel_launch(void* const* d_in, const int* in_sizes, int n_in,
                              void* d_out, int out_size, void* d_ws, size_t ws_size,
                              hipStream_t stream) {
  const int* ins_tok = (const int*)d_in[0];
  const int* his_tok = (const int*)d_in[1];
  const int* actions = (const int*)d_in[2];
  const int* cur_env = (const int*)d_in[3];
  const int* ini_env = (const int*)d_in[4];
  const float* enc_emb = (const float*)d_in[5];
  const float* Wih_f = (const float*)d_in[6];
  const float* Whh_f = (const float*)d_in[7];
  const float* bih_f = (const float*)d_in[8];
  const float* bhh_f = (const float*)d_in[9];
  const float* Wih_b = (const float*)d_in[10];
  const float* Whh_b = (const float*)d_in[11];
  const float* bih_b = (const float*)d_in[12];
  const float* bhh_b = (const float*)d_in[13];
  const float* color_emb = (const float*)d_in[14];
  const float* pos_emb = (const float*)d_in[15];
  const float* ws_Wih = (const float*)d_in[16];
  const float* ws_Whh = (const float*)d_in[17];
  const float* ws_bih = (const float*)d_in[18];
  const float* ws_bhh = (const float*)d_in[19];
  const float* act_emb = (const float*)d_in[20];
  const float* W_c = (const float*)d_in[21];
  const float* W_p = (const float*)d_in[22];
  const float* Wbd_W = (const float*)d_in[27];
  const float* dec_Wih = (const float*)d_in[29];
  const float* dec_Whh = (const float*)d_in[30];
  const float* dec_bih = (const float*)d_in[31];
  const float* dec_bhh = (const float*)d_in[32];
  const float* h2a_W = (const float*)d_in[33];
  const float* h2a_b = (const float*)d_in[34];
  const float* Wbd_b = (const float*)d_in[28];
  const float* h0 = (const float*)d_in[35];
  const float* c0 = (const float*)d_in[36];
  (void)in_sizes; (void)n_in; (void)out_size; (void)ws_size;

  char* ws = (char*)d_ws;
  size_t off = 0;
  auto alloc = [&](size_t bytes) -> char* {
    char* p = ws + off;
    off = (off + bytes + 255) & ~(size_t)255;
    return p;
  };
  u16* insenc   = (u16*)alloc(8192ull * 512 * 2);
  u16* hisenc   = (u16*)alloc(16384ull * 512 * 2);
  u16* outs     = (u16*)alloc(4096ull * 512 * 2);
  // overlay: proj tables (encoder-only) share space with A_c (decoder-only)
  char* ovl     = alloc(8192ull * 512 * 2);
  u16* A_c      = (u16*)ovl;
  u16* projf    = (u16*)ovl;
  u16* projb    = (u16*)(ovl + 2000ull * 1024 * 2);
  u16* wcT      = (u16*)alloc(512ull * 512 * 2);
  u16* Wsum     = (u16*)alloc(512ull * 896 * 2);
  float* projact= (float*)alloc(100ull * 512 * 4);
  float* bias_f = (float*)alloc(1024 * 4);
  float* bias_b = (float*)alloc(1024 * 4);
  float* bdecint= (float*)alloc(2048 * 4);
  float* bwbd   = (float*)alloc(512 * 4);
  float* bh2a   = (float*)alloc(128 * 4);
  u16* ctxcat   = (u16*)alloc(128ull * 896 * 2);
  float* hkbase = (float*)alloc(128ull * 512 * 4);
  float* u_p    = (float*)alloc(128ull * 512 * 4);
  u16* qbuf     = (u16*)alloc(128ull * 1024 * 2);
  u16* qattn    = (u16*)alloc(128ull * 1024 * 2);
  u16* zin      = (u16*)alloc(2ull * 128 * 1024 * 2);
  int* bars     = (int*)alloc(256);
  u16* emb_bf   = (u16*)alloc(2000ull * 128 * 2);
  u16* wihf_int = (u16*)alloc(1024ull * 128 * 2);
  u16* wihb_int = (u16*)alloc(1024ull * 128 * 2);
  u16* whhf_int = (u16*)alloc(1024ull * 256 * 2);
  u16* whhb_int = (u16*)alloc(1024ull * 256 * 2);
  u16* act_bf   = (u16*)alloc(100ull * 128 * 2);
  u16* wp_bf    = (u16*)alloc(512ull * 1024 * 2);
  u16* wbd01_bf = (u16*)alloc(512ull * 1024 * 2);
  u16* wbdx_bf  = (u16*)alloc(512ull * 128 * 2);
  u16* dwih_bf  = (u16*)alloc(2048ull * 512 * 2);
  u16* dwhh_bf  = (u16*)alloc(2048ull * 512 * 2);
  u16* h2a_bf   = (u16*)alloc(100ull * 512 * 2);

  // --- weight conversion (12 tensors; mode 1 = gate-interleave rows j*4+g) ---
  CvtAll ca{};
  const float* srcs[12] = {enc_emb, Wih_f, Wih_b, Whh_f, Whh_b, act_emb,
                           W_p, Wbd_W, Wbd_W, dec_Wih, dec_Whh, h2a_W};
  u16* dsts[12] = {emb_bf, wihf_int, wihb_int, whhf_int, whhb_int, act_bf,
                   wp_bf, wbd01_bf, wbdx_bf, dwih_bf, dwhh_bf, h2a_bf};
  int Rs[12]  = {2000, 1024, 1024, 1024, 1024, 100, 512, 512, 512, 2048, 2048, 100};
  int Cs[12]  = {128, 128, 128, 256, 256, 128, 1024, 1024, 128, 512, 512, 512};
  int ldsv[12]= {128, 128, 128, 256, 256, 128, 1024, 2944, 2944, 512, 512, 512};
  int c0s[12] = {0, 0, 0, 0, 0, 0, 0, 0, 2816, 0, 0, 0};
  int mds[12] = {0, 1, 1, 1, 1, 0, 0, 0, 0, 0, 0, 0};
  int blkacc = 0;
  for (int s = 0; s < 12; s++) {
    ca.src[s] = srcs[s]; ca.dst[s] = dsts[s];
    ca.R[s] = Rs[s]; ca.C[s] = Cs[s]; ca.ld[s] = ldsv[s]; ca.c0[s] = c0s[s]; ca.mode[s] = mds[s];
    ca.blk0[s] = blkacc;
    blkacc += (Rs[s] * Cs[s] + 255) / 256;
  }
  ca.blk0[12] = blkacc;
  cvt_all_k<<<blkacc, 256, 0, stream>>>(ca);
  cvt_T<<<1024, 256, 0, stream>>>(W_c, wcT);
  smallprep<<<19, 256, 0, stream>>>(bih_f, bhh_f, bih_b, bhh_b, Wbd_b, h2a_b,
                                    dec_bih, dec_bhh, bias_f, bias_b, bwbd, bh2a,
                                    bdecint, bars);
  wsum_build<<<1792, 256, 0, stream>>>(Wbd_W, Wsum);
  env_encode<<<224, 256, 0, stream>>>(cur_env, ini_env, color_emb, pos_emb,
                                      ws_Wih, ws_Whh, ws_bih, ws_bhh, ctxcat);

  // --- proj tables (bias folded, gate-interleaved cols) ---
  GemmArgs gf = {emb_bf, 128, 2000, wihf_int, 128, 1024, 128, projf, 1024, bias_f};
  gemm_k<1><<<dim3(32, 16), 256, 0, stream>>>(gf);
  GemmArgs gbk = {emb_bf, 128, 2000, wihb_int, 128, 1024, 128, projb, 1024, bias_b};
  gemm_k<1><<<dim3(32, 16), 256, 0, stream>>>(gbk);
  GemmArgs gp = {act_bf, 128, 100, wbdx_bf, 128, 512, 128, projact, 512, bwbd};
  gemm_k<0><<<dim3(2, 8), 256, 0, stream>>>(gp);
  GemmArgs gh = {ctxcat, 896, 128, Wsum, 896, 512, 896, hkbase, 512, nullptr};
  gemm_k<0><<<dim3(2, 8), 256, 0, stream>>>(gh);

  // --- encoder (barrier-free, block-local) ---
  enc_persist<<<32, 1024, 0, stream>>>(ins_tok, his_tok, whhf_int, whhb_int,
                                       projf, projb, insenc, hisenc);

  // --- A_c = insenc @ W_c (overwrites proj tables; encoder done) ---
  GemmArgs gc = {insenc, 512, 8192, wcT, 512, 512, 512, A_c, 512, nullptr};
  gemm_k<1><<<dim3(128, 8), 256, 0, stream>>>(gc);

  // --- decoder ---
  dec_persist<<<128, 256, 0, stream>>>(A_c, insenc, hisenc, wp_bf, wbd01_bf,
                                       dwih_bf, dwhh_bf, bdecint, hkbase, projact,
                                       actions, h0, c0, u_p, qbuf, qattn, zin, outs,
                                       bars);

  // --- logits ---
  GemmArgs gl = {outs, 512, 4096, h2a_bf, 512, 100, 512, d_out, 100, bh2a};
  gemm_k<0><<<dim3(64, 2), 256, 0, stream>>>(gl);
}